// Round 1
// baseline (177.419 us; speedup 1.0000x reference)
//
#include <hip/hip_runtime.h>

// ---------------------------------------------------------------------------
// MinConv2dLSTM: 2x (3x3 conv -> minLSTM gates -> scan over S)
// B=4 S=16 H=W=32, layer0: Cin=32, layer1: Cin=64, gates Cout=256 (4x64)
// Strategy: bf16 MFMA implicit GEMM for convs, fp32 gate math + scan.
// ---------------------------------------------------------------------------

typedef __bf16 bf16x8 __attribute__((ext_vector_type(8)));
typedef float f32x4 __attribute__((ext_vector_type(4)));

#define N_IMG 64      // B*S
#define HH 32
#define WW_ 32
#define HP 34         // padded
#define COUT 256

__device__ __forceinline__ float sigf(float x) { return 1.0f / (1.0f + __expf(-x)); }

__device__ __forceinline__ void gload16(void* lds, const void* g) {
  __builtin_amdgcn_global_load_lds(
      (const __attribute__((address_space(1))) void*)g,
      (__attribute__((address_space(3))) void*)lds, 16, 0, 0);
}

// ---------------------------------------------------------------------------
// pack_x: x (64,32,32,32) NCHW fp32 -> xT padded NHWC bf16 (64,34,34,32)
// halo assumed pre-zeroed (hipMemsetAsync). LDS transpose for coalescing.
// grid: 64*32 blocks (one per (n,h)), 256 threads.
// ---------------------------------------------------------------------------
__global__ __launch_bounds__(256) void pack_x_k(const float* __restrict__ x,
                                                __bf16* __restrict__ xT) {
  __shared__ float ls[32][33];
  const int n = blockIdx.x >> 5;
  const int h = blockIdx.x & 31;
  const int t = threadIdx.x;
  {
    const int w = t & 31, g4 = t >> 5;           // 8 groups x 4 ci
    const float* src = x + (((size_t)n * 32) << 10) + (h << 5);
#pragma unroll
    for (int j = 0; j < 4; ++j) {
      int ci = g4 * 4 + j;
      ls[ci][w] = src[((size_t)ci << 10) + w];
    }
  }
  __syncthreads();
  {
    const int ci = t & 31, w4 = t >> 5;
    __bf16* dst = xT + ((size_t)(n * HP + h + 1) * HP + 1) * 32 + ci;
#pragma unroll
    for (int j = 0; j < 4; ++j) {
      int w = w4 * 4 + j;
      dst[w * 32] = (__bf16)ls[ci][w];
    }
  }
}

// ---------------------------------------------------------------------------
// pack_w: w (256,CIN,3,3) fp32 -> wT [co][kh*3+kw][ci] bf16
// ---------------------------------------------------------------------------
template <int CIN>
__global__ __launch_bounds__(256) void pack_w_k(const float* __restrict__ w,
                                                __bf16* __restrict__ wT) {
  int g = blockIdx.x * 256 + threadIdx.x;
  if (g >= 256 * 9 * CIN) return;
  int co = g / (9 * CIN);
  int r = g - co * 9 * CIN;
  int khkw = r / CIN;
  int ci = r - khkw * CIN;
  wT[g] = (__bf16)w[(size_t)(co * CIN + ci) * 9 + khkw];
}

// ---------------------------------------------------------------------------
// conv_gemm: implicit-GEMM 3x3 conv, bf16 MFMA 16x16x32.
// Block: 256 thr = 4 waves, tile 128(m=pixels) x 128(n=cout), 9 K-steps of CIN.
// LDS layout: [chunk16B][row] so frag ds_read_b128 is conflict-free and
// global_load_lds linear-dest (1KB per call = one chunk x 64 rows) matches.
// LAYER1=false: D[pixel][co], store gates[m*256+co]   (m = n*1024+p)
// LAYER1=true : D[co][pixel], store gates[(n*256+co)*1024+p]
// ---------------------------------------------------------------------------
template <int CIN, bool LAYER1>
__global__ __launch_bounds__(256, 2) void conv_gemm_k(
    const __bf16* __restrict__ xT,   // padded NHWC (64,34,34,CIN)
    const __bf16* __restrict__ wT,   // [256][9*CIN]
    const float* __restrict__ bias,  // [256]
    __bf16* __restrict__ gates) {
  constexpr int BK = CIN;          // K per step
  constexpr int NKK = BK / 32;     // MFMAs per frag pair per step
  constexpr int CHUNKS = BK / 8;   // 16B chunks per row
  __shared__ bf16x8 lsA[CHUNKS * 128];
  __shared__ bf16x8 lsB[CHUNKS * 128];

  const int tid = threadIdx.x;
  const int lane = tid & 63;
  const int wid = tid >> 6;
  const int wr = wid >> 1, wc = wid & 1;  // wave 64x64 sub-tile

  const int bx = blockIdx.x;        // m-block: 8 per image
  const int by = blockIdx.y;        // co-block (2)
  const int n = bx >> 3;
  const int h0 = (bx & 7) << 2;     // 4 image rows per block
  const int co0 = by << 7;

  f32x4 acc[4][4] = {};

  const size_t wrow = (size_t)9 * CIN;

  for (int t = 0; t < 9; ++t) {
    const int kh = t / 3;
    const int kw = t - kh * 3;
    // --- stage A (x im2col slice): rows=128 pixels, cols=CIN (one (kh,kw))
    for (int c = wid; c < 2 * CHUNKS; c += 4) {
      const int chunk = c >> 1;
      const int pix = ((c & 1) << 6) + lane;
      const int hh = h0 + (pix >> 5) + kh;   // padded row index
      const int ww = (pix & 31) + kw;        // padded col index
      const __bf16* src = xT + ((size_t)(n * HP + hh) * HP + ww) * CIN + chunk * 8;
      gload16((void*)(lsA + c * 64), (const void*)src);
    }
    // --- stage B (weights slice): rows=128 co, cols=CIN
    for (int c = wid; c < 2 * CHUNKS; c += 4) {
      const int chunk = c >> 1;
      const int row = ((c & 1) << 6) + lane;
      const __bf16* src = wT + (size_t)(co0 + row) * wrow + t * CIN + chunk * 8;
      gload16((void*)(lsB + c * 64), (const void*)src);
    }
    __syncthreads();
#pragma unroll
    for (int kk = 0; kk < NKK; ++kk) {
      const int ca = kk * 4 + (lane >> 4);
      bf16x8 af[4], wf[4];
#pragma unroll
      for (int mi = 0; mi < 4; ++mi)
        af[mi] = lsA[ca * 128 + wr * 64 + mi * 16 + (lane & 15)];
#pragma unroll
      for (int ni = 0; ni < 4; ++ni)
        wf[ni] = lsB[ca * 128 + wc * 64 + ni * 16 + (lane & 15)];
#pragma unroll
      for (int mi = 0; mi < 4; ++mi)
#pragma unroll
        for (int ni = 0; ni < 4; ++ni) {
          if constexpr (!LAYER1)
            acc[mi][ni] = __builtin_amdgcn_mfma_f32_16x16x32_bf16(
                af[mi], wf[ni], acc[mi][ni], 0, 0, 0);
          else
            acc[mi][ni] = __builtin_amdgcn_mfma_f32_16x16x32_bf16(
                wf[ni], af[mi], acc[mi][ni], 0, 0, 0);
        }
    }
    __syncthreads();
  }

  // epilogue: C/D map col=lane&15, row=(lane>>4)*4+r
#pragma unroll
  for (int mi = 0; mi < 4; ++mi)
#pragma unroll
    for (int ni = 0; ni < 4; ++ni)
#pragma unroll
      for (int r = 0; r < 4; ++r) {
        if constexpr (!LAYER1) {
          const int m_loc = wr * 64 + mi * 16 + ((lane >> 4) << 2) + r;
          const int co = co0 + wc * 64 + ni * 16 + (lane & 15);
          const size_t m = (size_t)bx * 128 + m_loc;
          gates[m * 256 + co] = (__bf16)(acc[mi][ni][r] + bias[co]);
        } else {
          const int co = co0 + wc * 64 + ni * 16 + ((lane >> 4) << 2) + r;
          const int m_loc = wr * 64 + mi * 16 + (lane & 15);
          const int m = bx * 128 + m_loc;
          const int nimg = m >> 10, p = m & 1023;
          gates[((size_t)nimg * 256 + co) * 1024 + p] =
              (__bf16)(acc[mi][ni][r] + bias[co]);
        }
      }
}

// ---------------------------------------------------------------------------
// scan0: gates [m][256] bf16 -> h0T padded NHWC bf16 (64,34,34,64)
// thread = (b, p, c), lanes over c (coalesced both sides). 1024 blocks x 256.
// ---------------------------------------------------------------------------
__global__ __launch_bounds__(256) void scan0_k(const __bf16* __restrict__ gates,
                                               __bf16* __restrict__ h0T) {
  const int g = blockIdx.x * 256 + threadIdx.x;  // 4*1024*64
  const int c = g & 63;
  const int p = (g >> 6) & 1023;
  const int b = g >> 16;
  const int h = p >> 5, w = p & 31;
  float cst = 0.5f;
#pragma unroll 4
  for (int s = 0; s < 16; ++s) {
    const size_t base = ((size_t)((b * 16 + s) * 1024 + p)) * 256 + c;
    const float ig_ = (float)gates[base];
    const float fg_ = (float)gates[base + 64];
    const float og_ = (float)gates[base + 128];
    const float cd_ = (float)gates[base + 192];
    const float it = sigf(ig_), ft = sigf(fg_);
    const float inv = 1.0f / (it + ft);
    const float gc = (cd_ >= 0.0f) ? (cd_ + 0.5f) : sigf(cd_);
    cst = (ft * inv) * cst + (it * inv) * gc;
    const float hv = sigf(og_) * cst;
    h0T[((size_t)((b * 16 + s) * HP + h + 1) * HP + (w + 1)) * 64 + c] =
        (__bf16)hv;
  }
}

// ---------------------------------------------------------------------------
// scan1: gates [n][256][1024] bf16 -> out fp32 (B,S,64,32,32)
// thread = (b, c, p), lanes over p (coalesced both sides).
// ---------------------------------------------------------------------------
__global__ __launch_bounds__(256) void scan1_k(const __bf16* __restrict__ gates,
                                               float* __restrict__ out) {
  const int g = blockIdx.x * 256 + threadIdx.x;
  const int p = g & 1023;
  const int c = (g >> 10) & 63;
  const int b = g >> 16;
  float cst = 0.5f;
#pragma unroll 4
  for (int s = 0; s < 16; ++s) {
    const size_t nb = (size_t)(b * 16 + s) * 256;
    const size_t base = (nb + c) * 1024 + p;
    const float ig_ = (float)gates[base];
    const float fg_ = (float)gates[base + 64 * 1024];
    const float og_ = (float)gates[base + 128 * 1024];
    const float cd_ = (float)gates[base + 192 * 1024];
    const float it = sigf(ig_), ft = sigf(fg_);
    const float inv = 1.0f / (it + ft);
    const float gc = (cd_ >= 0.0f) ? (cd_ + 0.5f) : sigf(cd_);
    cst = (ft * inv) * cst + (it * inv) * gc;
    const float hv = sigf(og_) * cst;
    out[((size_t)((b * 16 + s) * 64 + c)) * 1024 + p] = hv;
  }
}

// ---------------------------------------------------------------------------
extern "C" void kernel_launch(void* const* d_in, const int* in_sizes, int n_in,
                              void* d_out, int out_size, void* d_ws,
                              size_t ws_size, hipStream_t stream) {
  const float* x = (const float*)d_in[0];   // (4,16,32,32,32)
  const float* w0 = (const float*)d_in[1];  // (256,32,3,3)
  const float* b0 = (const float*)d_in[2];  // (256)
  const float* w1 = (const float*)d_in[3];  // (256,64,3,3)
  const float* b1 = (const float*)d_in[4];  // (256)
  float* out = (float*)d_out;               // (4,16,64,32,32)

  char* ws = (char*)d_ws;
  const size_t XT_BYTES = (size_t)N_IMG * HP * HP * 32 * 2;   // 4,734,976
  const size_t H0_BYTES = (size_t)N_IMG * HP * HP * 64 * 2;   // 9,469,952
  const size_t W0T_BYTES = (size_t)256 * 9 * 32 * 2;          // 147,456
  const size_t W1T_BYTES = (size_t)256 * 9 * 64 * 2;          // 294,912
  __bf16* xT = (__bf16*)ws;
  __bf16* h0T = (__bf16*)(ws + XT_BYTES);
  __bf16* w0T = (__bf16*)(ws + XT_BYTES + H0_BYTES);
  __bf16* w1T = (__bf16*)(ws + XT_BYTES + H0_BYTES + W0T_BYTES);
  __bf16* gates = (__bf16*)(ws + XT_BYTES + H0_BYTES + W0T_BYTES + W1T_BYTES);
  (void)ws_size; (void)n_in; (void)in_sizes; (void)out_size;

  // zero padded buffers (halo must be re-zeroed every call: ws is re-poisoned)
  hipMemsetAsync(xT, 0, XT_BYTES, stream);
  hipMemsetAsync(h0T, 0, H0_BYTES, stream);

  pack_x_k<<<N_IMG * 32, 256, 0, stream>>>(x, xT);
  pack_w_k<32><<<(256 * 9 * 32 + 255) / 256, 256, 0, stream>>>(w0, w0T);
  pack_w_k<64><<<(256 * 9 * 64 + 255) / 256, 256, 0, stream>>>(w1, w1T);

  // layer 0
  conv_gemm_k<32, false><<<dim3(512, 2), 256, 0, stream>>>(xT, w0T, b0, gates);
  scan0_k<<<1024, 256, 0, stream>>>(gates, h0T);
  // layer 1
  conv_gemm_k<64, true><<<dim3(512, 2), 256, 0, stream>>>(h0T, w1T, b1, gates);
  scan1_k<<<1024, 256, 0, stream>>>(gates, out);
}